// Round 20
// baseline (84.346 us; speedup 1.0000x reference)
//
#include <hip/hip_runtime.h>

#define NS 65536      // stocks
#define HID 512       // hidden
#define NE 128        // industries
#define PC 32         // stock-windows in aggregation (window-major dispatch)
#define NEG 0.01f     // LeakyReLU slope

typedef int   vi4 __attribute__((ext_vector_type(4)));
typedef float vf4 __attribute__((ext_vector_type(4)));

// ---------------------------------------------------------------------------
// K1: decode one-hot rows -> ind[s]. Nontemporal vi4 loads (r13 config).
__global__ __launch_bounds__(1024) void k_find(const int* __restrict__ im,
                                               int* __restrict__ ind) {
    __shared__ int lind[256];
    const int b = blockIdx.x, t = threadIdx.x;
    const vi4* p = reinterpret_cast<const vi4*>(im) + (size_t)b * 8192;
#pragma unroll
    for (int j = t; j < 8192; j += 1024) {   // 256 rows x 32 vi4, 8 iters
        vi4 v = __builtin_nontemporal_load(p + j);
        int s = j >> 5;          // local row
        int c = (j & 31) << 2;   // column of v[0]
        if (v[0] == 1) lind[s] = c;
        if (v[1] == 1) lind[s] = c + 1;
        if (v[2] == 1) lind[s] = c + 2;
        if (v[3] == 1) lind[s] = c + 3;
    }
    __syncthreads();
    if (t < 256) ind[b * 256 + t] = lind[t];
}

// ---------------------------------------------------------------------------
// K2: per-industry row-sum, WINDOW-MAJOR: block = q*128+e, so the 128
// consecutively-dispatched blocks share one 2048-stock (4 MB) window and
// read it densely -> DRAM page locality for the gather. Each block scans
// 2048 ind entries (8 KB, L2), compacts ~16 rows, gathers their 2 KB e_s
// rows (NT vf4). Writes disjoint partial[q][e][:] + counts[q][e].
__global__ __launch_bounds__(512) void k_agg(const float* __restrict__ e_s,
                                             const int* __restrict__ ind,
                                             float* __restrict__ partial,
                                             int* __restrict__ counts) {
    __shared__ int rows[512];
    __shared__ vf4 red[512];
    __shared__ int cntL;
    const int e = blockIdx.x & (NE - 1);   // industry (fast axis)
    const int q = blockIdx.x >> 7;         // stock window (slow axis)
    const int t = threadIdx.x;
    if (t == 0) cntL = 0;
    __syncthreads();
    const int base = q * (NS / PC);        // 2048-stock window
#pragma unroll
    for (int k = 0; k < (NS / PC) / 512; ++k) {   // 4 coalesced L2 reads
        int idx = base + k * 512 + t;
        if (ind[idx] == e) {
            int p = atomicAdd(&cntL, 1);          // LDS atomic append
            if (p < 512) rows[p] = idx;
        }
    }
    __syncthreads();
    const int cnt = (cntL < 512) ? cntL : 512;    // ~16 expected
    const int g = t >> 7;        // 4 row-groups
    const int l = t & 127;       // vf4 column
    vf4 acc = {0.f, 0.f, 0.f, 0.f};
#pragma unroll 4
    for (int i = g; i < cnt; i += 4) {
        int row = rows[i];       // group-uniform broadcast
        vf4 v = __builtin_nontemporal_load(
            reinterpret_cast<const vf4*>(e_s + (size_t)row * HID) + l);
        acc += v;
    }
    red[t] = acc;
    __syncthreads();
    if (g == 0) {
        vf4 a = red[l];
#pragma unroll
        for (int p = 1; p < 4; ++p) a += red[l + p * 128];
        reinterpret_cast<vf4*>(partial + ((size_t)(q * NE + e)) * HID)[l] = a;
    }
    if (t == 0) counts[q * NE + e] = cnt;
}

// ---------------------------------------------------------------------------
// K3: efrow[e] = LeakyReLU(Binv * (sum_q partial_q[e]) @ W + bias).
__global__ __launch_bounds__(1024) void k_gemm(const float* __restrict__ partial,
                                               const float* __restrict__ W,
                                               const float* __restrict__ bias,
                                               const int* __restrict__ counts,
                                               float* __restrict__ efrow) {
    __shared__ float aL[HID];
    __shared__ float redf[1024];
    const int e = blockIdx.x;
    const int t = threadIdx.x;
    if (t < HID) {
        float s = 0.f;
#pragma unroll 8
        for (int q = 0; q < PC; ++q) s += partial[((size_t)(q * NE + e)) * HID + t];
        aL[t] = s;
    }
    __syncthreads();
    const int j  = t & (HID - 1);
    const int hh = t >> 9;            // K-half: 0 or 1
    const int k0 = hh * 256;
    float acc = 0.f;
#pragma unroll 8
    for (int k = k0; k < k0 + 256; ++k)
        acc += aL[k] * W[k * HID + j];   // aL: LDS broadcast; W: coalesced/L2
    redf[t] = acc;
    __syncthreads();
    if (t < HID) {
        int tot = 0;
#pragma unroll 8
        for (int q = 0; q < PC; ++q) tot += counts[q * NE + e];
        float binv = (tot > 0) ? 1.0f / (float)tot : 0.0f;
        float v = (redf[t] + redf[t + HID]) * binv + bias[t];
        efrow[(size_t)e * HID + t] = (v >= 0.0f) ? v : NEG * v;
    }
}

// ---------------------------------------------------------------------------
// K4: stock-major output. Sequential NT stores (r13 config).
__global__ __launch_bounds__(1024) void k_out(const float* __restrict__ efrow,
                                              const int* __restrict__ ind,
                                              float* __restrict__ out) {
    __shared__ int lindL[256];
    const int b = blockIdx.x, t = threadIdx.x;
    if (t < 256) lindL[t] = ind[b * 256 + t];
    __syncthreads();
    const int g = t >> 7;        // 8 groups: one stock-row per group per iter
    const int l = t & 127;       // vf4 lane within row
    vf4* outp = reinterpret_cast<vf4*>(out) + (size_t)b * 256 * 128;
#pragma unroll 4
    for (int ls = g; ls < 256; ls += 8) {
        int e = lindL[ls];       // wave-uniform broadcast
        vf4 v = reinterpret_cast<const vf4*>(efrow + (size_t)e * HID)[l];
        __builtin_nontemporal_store(v, outp + ls * 128 + l);
    }
}

extern "C" void kernel_launch(void* const* d_in, const int* in_sizes, int n_in,
                              void* d_out, int out_size, void* d_ws, size_t ws_size,
                              hipStream_t stream) {
    const float* e_s  = (const float*)d_in[0];
    const int*   im   = (const int*)d_in[1];
    const float* W    = (const float*)d_in[2];
    const float* bias = (const float*)d_in[3];
    float* out = (float*)d_out;

    char* ws = (char*)d_ws;
    // layout: ind 256KB @0 | partial 8MB @256K | counts 16KB @8.25MB
    //         | efrow 256KB @8.5MB
    int*   ind     = (int*)(ws + 0);
    float* partial = (float*)(ws + 262144);
    int*   counts  = (int*)(ws + 8650752);
    float* efrow   = (float*)(ws + 8912896);

    k_find<<<256, 1024, 0, stream>>>(im, ind);
    k_agg <<<NE * PC, 512, 0, stream>>>(e_s, ind, partial, counts);
    k_gemm<<<NE, 1024, 0, stream>>>(partial, W, bias, counts, efrow);
    k_out <<<256, 1024, 0, stream>>>(efrow, ind, out);
}

// Round 21
// 78.753 us; speedup vs baseline: 1.0710x; 1.0710x over previous
//
#include <hip/hip_runtime.h>

#define NS 65536      // stocks
#define HID 512       // hidden
#define NE 128        // industries
#define NEG 0.01f     // LeakyReLU slope

typedef int   vi4 __attribute__((ext_vector_type(4)));
typedef float vf4 __attribute__((ext_vector_type(4)));

// ---------------------------------------------------------------------------
// K1: decode one-hot rows -> ind[s]. Nontemporal vi4 loads (r13 config).
__global__ __launch_bounds__(1024) void k_find(const int* __restrict__ im,
                                               int* __restrict__ ind) {
    __shared__ int lind[256];
    const int b = blockIdx.x, t = threadIdx.x;
    const vi4* p = reinterpret_cast<const vi4*>(im) + (size_t)b * 8192;
#pragma unroll
    for (int j = t; j < 8192; j += 1024) {   // 256 rows x 32 vi4, 8 iters
        vi4 v = __builtin_nontemporal_load(p + j);
        int s = j >> 5;          // local row
        int c = (j & 31) << 2;   // column of v[0]
        if (v[0] == 1) lind[s] = c;
        if (v[1] == 1) lind[s] = c + 1;
        if (v[2] == 1) lind[s] = c + 2;
        if (v[3] == 1) lind[s] = c + 3;
    }
    __syncthreads();
    if (t < 256) ind[b * 256 + t] = lind[t];
}

// ---------------------------------------------------------------------------
// K2: per-industry row-sum with self-compaction (r13 structure). Single
// change: gather loop unroll 4 -> 8 for deeper memory-level parallelism
// against ~900-cycle cold-HBM latency.
__global__ __launch_bounds__(1024) void k_agg(const float* __restrict__ e_s,
                                              const int* __restrict__ ind,
                                              float* __restrict__ partial,
                                              int* __restrict__ counts) {
    __shared__ int rows[1024];
    __shared__ vf4 red[1024];
    __shared__ int cntL;
    const int e = blockIdx.x >> 2;
    const int q = blockIdx.x & 3;
    const int t = threadIdx.x;
    if (t == 0) cntL = 0;
    __syncthreads();
    const int base = q * (NS / 4);
#pragma unroll
    for (int k = 0; k < (NS / 4) / 1024; ++k) {   // 16 coalesced L2 reads
        int idx = base + k * 1024 + t;
        if (ind[idx] == e) {
            int p = atomicAdd(&cntL, 1);          // LDS atomic append
            if (p < 1024) rows[p] = idx;
        }
    }
    __syncthreads();
    const int cnt = (cntL < 1024) ? cntL : 1024;  // ~128 expected
    const int g = t >> 7;        // 8 row-groups
    const int l = t & 127;       // vf4 column
    vf4 acc = {0.f, 0.f, 0.f, 0.f};
#pragma unroll 8
    for (int i = g; i < cnt; i += 8) {
        int row = rows[i];       // wave-uniform broadcast
        vf4 v = __builtin_nontemporal_load(
            reinterpret_cast<const vf4*>(e_s + (size_t)row * HID) + l);
        acc += v;
    }
    red[t] = acc;
    __syncthreads();
    if (g == 0) {
        vf4 a = red[l];
#pragma unroll
        for (int p = 1; p < 8; ++p) a += red[l + p * 128];
        reinterpret_cast<vf4*>(partial + ((size_t)(q * NE + e)) * HID)[l] = a;
    }
    if (t == 0) counts[q * NE + e] = cnt;
}

// ---------------------------------------------------------------------------
// K3: efrow[e] = LeakyReLU(Binv * (sum_q partial_q[e]) @ W + bias).
__global__ __launch_bounds__(1024) void k_gemm(const float* __restrict__ partial,
                                               const float* __restrict__ W,
                                               const float* __restrict__ bias,
                                               const int* __restrict__ counts,
                                               float* __restrict__ efrow) {
    __shared__ float aL[HID];
    __shared__ float redf[1024];
    const int e = blockIdx.x;
    const int t = threadIdx.x;
    if (t < HID) {
        float s = 0.f;
#pragma unroll
        for (int q = 0; q < 4; ++q) s += partial[((size_t)(q * NE + e)) * HID + t];
        aL[t] = s;
    }
    __syncthreads();
    const int j  = t & (HID - 1);
    const int hh = t >> 9;            // K-half: 0 or 1
    const int k0 = hh * 256;
    float acc = 0.f;
#pragma unroll 8
    for (int k = k0; k < k0 + 256; ++k)
        acc += aL[k] * W[k * HID + j];   // aL: LDS broadcast; W: coalesced/L2
    redf[t] = acc;
    __syncthreads();
    if (t < HID) {
        int tot = counts[e] + counts[NE + e] + counts[2 * NE + e] + counts[3 * NE + e];
        float binv = (tot > 0) ? 1.0f / (float)tot : 0.0f;
        float v = (redf[t] + redf[t + HID]) * binv + bias[t];
        efrow[(size_t)e * HID + t] = (v >= 0.0f) ? v : NEG * v;
    }
}

// ---------------------------------------------------------------------------
// K4: stock-major output (r13 structure). Store loop unroll 4 -> 8.
__global__ __launch_bounds__(1024) void k_out(const float* __restrict__ efrow,
                                              const int* __restrict__ ind,
                                              float* __restrict__ out) {
    __shared__ int lindL[256];
    const int b = blockIdx.x, t = threadIdx.x;
    if (t < 256) lindL[t] = ind[b * 256 + t];
    __syncthreads();
    const int g = t >> 7;        // 8 groups: one stock-row per group per iter
    const int l = t & 127;       // vf4 lane within row
    vf4* outp = reinterpret_cast<vf4*>(out) + (size_t)b * 256 * 128;
#pragma unroll 8
    for (int ls = g; ls < 256; ls += 8) {
        int e = lindL[ls];       // wave-uniform broadcast
        vf4 v = reinterpret_cast<const vf4*>(efrow + (size_t)e * HID)[l];
        __builtin_nontemporal_store(v, outp + ls * 128 + l);
    }
}

extern "C" void kernel_launch(void* const* d_in, const int* in_sizes, int n_in,
                              void* d_out, int out_size, void* d_ws, size_t ws_size,
                              hipStream_t stream) {
    const float* e_s  = (const float*)d_in[0];
    const int*   im   = (const int*)d_in[1];
    const float* W    = (const float*)d_in[2];
    const float* bias = (const float*)d_in[3];
    float* out = (float*)d_out;

    char* ws = (char*)d_ws;
    // layout: ind 256KB @0 | partial 1MB @256K | counts 2KB @1.25MB
    //         | efrow 256KB @1.5MB
    int*   ind     = (int*)(ws + 0);
    float* partial = (float*)(ws + 262144);
    int*   counts  = (int*)(ws + 1310720);
    float* efrow   = (float*)(ws + 1572864);

    k_find<<<256, 1024, 0, stream>>>(im, ind);
    k_agg <<<NE * 4, 1024, 0, stream>>>(e_s, ind, partial, counts);
    k_gemm<<<NE, 1024, 0, stream>>>(partial, W, bias, counts, efrow);
    k_out <<<256, 1024, 0, stream>>>(efrow, ind, out);
}

// Round 22
// 76.317 us; speedup vs baseline: 1.1052x; 1.0319x over previous
//
#include <hip/hip_runtime.h>

#define NS 65536      // stocks
#define HID 512       // hidden
#define NE 128        // industries
#define NEG 0.01f     // LeakyReLU slope

typedef int   vi4 __attribute__((ext_vector_type(4)));
typedef float vf4 __attribute__((ext_vector_type(4)));

// ---------------------------------------------------------------------------
// K1: decode one-hot rows -> ind[s]. Nontemporal vi4 loads (r13 config).
__global__ __launch_bounds__(1024) void k_find(const int* __restrict__ im,
                                               int* __restrict__ ind) {
    __shared__ int lind[256];
    const int b = blockIdx.x, t = threadIdx.x;
    const vi4* p = reinterpret_cast<const vi4*>(im) + (size_t)b * 8192;
#pragma unroll
    for (int j = t; j < 8192; j += 1024) {   // 256 rows x 32 vi4, 8 iters
        vi4 v = __builtin_nontemporal_load(p + j);
        int s = j >> 5;          // local row
        int c = (j & 31) << 2;   // column of v[0]
        if (v[0] == 1) lind[s] = c;
        if (v[1] == 1) lind[s] = c + 1;
        if (v[2] == 1) lind[s] = c + 2;
        if (v[3] == 1) lind[s] = c + 3;
    }
    __syncthreads();
    if (t < 256) ind[b * 256 + t] = lind[t];
}

// ---------------------------------------------------------------------------
// K2: per-industry row-sum with self-compaction (r13 exact: unroll 4).
__global__ __launch_bounds__(1024) void k_agg(const float* __restrict__ e_s,
                                              const int* __restrict__ ind,
                                              float* __restrict__ partial,
                                              int* __restrict__ counts) {
    __shared__ int rows[1024];
    __shared__ vf4 red[1024];
    __shared__ int cntL;
    const int e = blockIdx.x >> 2;
    const int q = blockIdx.x & 3;
    const int t = threadIdx.x;
    if (t == 0) cntL = 0;
    __syncthreads();
    const int base = q * (NS / 4);
#pragma unroll
    for (int k = 0; k < (NS / 4) / 1024; ++k) {   // 16 coalesced L2 reads
        int idx = base + k * 1024 + t;
        if (ind[idx] == e) {
            int p = atomicAdd(&cntL, 1);          // LDS atomic append
            if (p < 1024) rows[p] = idx;
        }
    }
    __syncthreads();
    const int cnt = (cntL < 1024) ? cntL : 1024;  // ~128 expected
    const int g = t >> 7;        // 8 row-groups
    const int l = t & 127;       // vf4 column
    vf4 acc = {0.f, 0.f, 0.f, 0.f};
#pragma unroll 4
    for (int i = g; i < cnt; i += 8) {
        int row = rows[i];       // wave-uniform broadcast
        vf4 v = __builtin_nontemporal_load(
            reinterpret_cast<const vf4*>(e_s + (size_t)row * HID) + l);
        acc += v;
    }
    red[t] = acc;
    __syncthreads();
    if (g == 0) {
        vf4 a = red[l];
#pragma unroll
        for (int p = 1; p < 8; ++p) a += red[l + p * 128];
        reinterpret_cast<vf4*>(partial + ((size_t)(q * NE + e)) * HID)[l] = a;
    }
    if (t == 0) counts[q * NE + e] = cnt;
}

// ---------------------------------------------------------------------------
// K3: efrow[e] = LeakyReLU(Binv * (sum_q partial_q[e]) @ W + bias).
__global__ __launch_bounds__(1024) void k_gemm(const float* __restrict__ partial,
                                               const float* __restrict__ W,
                                               const float* __restrict__ bias,
                                               const int* __restrict__ counts,
                                               float* __restrict__ efrow) {
    __shared__ float aL[HID];
    __shared__ float redf[1024];
    const int e = blockIdx.x;
    const int t = threadIdx.x;
    if (t < HID) {
        float s = 0.f;
#pragma unroll
        for (int q = 0; q < 4; ++q) s += partial[((size_t)(q * NE + e)) * HID + t];
        aL[t] = s;
    }
    __syncthreads();
    const int j  = t & (HID - 1);
    const int hh = t >> 9;            // K-half: 0 or 1
    const int k0 = hh * 256;
    float acc = 0.f;
#pragma unroll 8
    for (int k = k0; k < k0 + 256; ++k)
        acc += aL[k] * W[k * HID + j];   // aL: LDS broadcast; W: coalesced/L2
    redf[t] = acc;
    __syncthreads();
    if (t < HID) {
        int tot = counts[e] + counts[NE + e] + counts[2 * NE + e] + counts[3 * NE + e];
        float binv = (tot > 0) ? 1.0f / (float)tot : 0.0f;
        float v = (redf[t] + redf[t + HID]) * binv + bias[t];
        efrow[(size_t)e * HID + t] = (v >= 0.0f) ? v : NEG * v;
    }
}

// ---------------------------------------------------------------------------
// K4: fill-style output: 2048 blocks x 256 threads, grid-stride over vf4
// elements, PLAIN stores (mimics the harness fill kernel that demonstrates
// 7.1 TB/s writes). ind read per half-row (L2-hot), efrow from L2.
__global__ __launch_bounds__(256) void k_out(const float* __restrict__ efrow,
                                             const int* __restrict__ ind,
                                             float* __restrict__ out) {
    const int total = NS * (HID / 4);      // vf4 elements: 8388608
    vf4* outp = reinterpret_cast<vf4*>(out);
    for (int i = blockIdx.x * 256 + threadIdx.x; i < total;
         i += 2048 * 256) {
        int s  = i >> 7;                   // stock row (uniform per half-wave)
        int c4 = i & 127;                  // vf4 lane within row
        int e  = ind[s];                   // L2-hot scalar load
        vf4 v = reinterpret_cast<const vf4*>(efrow + (size_t)e * HID)[c4];
        outp[i] = v;
    }
}

extern "C" void kernel_launch(void* const* d_in, const int* in_sizes, int n_in,
                              void* d_out, int out_size, void* d_ws, size_t ws_size,
                              hipStream_t stream) {
    const float* e_s  = (const float*)d_in[0];
    const int*   im   = (const int*)d_in[1];
    const float* W    = (const float*)d_in[2];
    const float* bias = (const float*)d_in[3];
    float* out = (float*)d_out;

    char* ws = (char*)d_ws;
    // layout: ind 256KB @0 | partial 1MB @256K | counts 2KB @1.25MB
    //         | efrow 256KB @1.5MB
    int*   ind     = (int*)(ws + 0);
    float* partial = (float*)(ws + 262144);
    int*   counts  = (int*)(ws + 1310720);
    float* efrow   = (float*)(ws + 1572864);

    k_find<<<256, 1024, 0, stream>>>(im, ind);
    k_agg <<<NE * 4, 1024, 0, stream>>>(e_s, ind, partial, counts);
    k_gemm<<<NE, 1024, 0, stream>>>(partial, W, bias, counts, efrow);
    k_out <<<2048, 256, 0, stream>>>(efrow, ind, out);
}